// Round 5
// baseline (1712.447 us; speedup 1.0000x reference)
//
#include <hip/hip_runtime.h>
#include <cstdint>
#include <cstddef>

// ---------------- problem constants ----------------
static constexpr int Bc = 4, Nc = 4096, Dc = 768, Hc = 12, DHc = 64;
static constexpr int HIDc = 3072, DEPTHc = 4;
static constexpr int Mc = Bc * Nc;        // 16384 rows
static constexpr int BHc = Bc * Hc;       // 48
static constexpr int BHDc = BHc * DHc;    // 3072

typedef unsigned short u16;
typedef __bf16 bf16x8 __attribute__((ext_vector_type(8)));
typedef float  f32x4  __attribute__((ext_vector_type(4)));

#define DEV __device__ __forceinline__

DEV u16 f2bf(float x) {            // RNE float->bf16
    uint32_t u = __float_as_uint(x);
    u += 0x7fffu + ((u >> 16) & 1u);
    return (u16)(u >> 16);
}
DEV float bf2f(u16 u) { return __uint_as_float(((uint32_t)u) << 16); }
DEV void unp2(uint32_t u, float& a, float& b) {   // packed bf16 pair -> 2 fp32
    a = __uint_as_float(u << 16);
    b = __uint_as_float(u & 0xffff0000u);
}
DEV float gelu_fast(float x) {     // tanh-form GELU, |err|<3e-3 vs exact erf form
    float y = 0.7978845608f * (x + 0.044715f * x * x * x);
    float e = __expf(2.0f * y);
    float t = 1.0f - 2.0f / (e + 1.0f);
    return 0.5f * x * (1.0f + t);
}

// global -> LDS direct (16B per lane). LDS dest = wave-uniform base + lane*16.
DEV void ldg_lds16(const void* g, void* l) {
    __builtin_amdgcn_global_load_lds(
        (const __attribute__((address_space(1))) uint32_t*)(uintptr_t)g,
        (__attribute__((address_space(3))) uint32_t*)(uint32_t)(uintptr_t)l,
        16, 0, 0);
}

// ---------------- input dtype sniffer (robustness; measured: fp32) ----------------
__global__ void detect_kernel(const uint32_t* __restrict__ x, uint32_t* __restrict__ flag) {
    int t = threadIdx.x;
    uint32_t w = x[t];
    int e = (w >> 7) & 0xFF;
    __shared__ int cnt[256];
    cnt[t] = (e >= 100 && e <= 140) ? 1 : 0;
    __syncthreads();
    for (int s = 128; s; s >>= 1) {
        if (t < s) cnt[t] += cnt[t + s];
        __syncthreads();
    }
    if (t == 0) flag[0] = (cnt[0] >= 128) ? 1u : 0u;
}

// sentinel: absmax ~1234 == "workspace too small"
__global__ __launch_bounds__(256) void sentinel_kernel(u16* __restrict__ out, int n) {
    int i = blockIdx.x * 256 + threadIdx.x;
    if (i < n) out[i] = 0x449A;
}

__global__ __launch_bounds__(256) void cvt_param_kernel(
    const void* __restrict__ src, float* __restrict__ dst, int n,
    const uint32_t* __restrict__ flag) {
    int i = blockIdx.x * 256 + threadIdx.x;
    if (i >= n) return;
    if (flag[0]) dst[i] = bf2f(((const u16*)src)[i]);
    else         dst[i] = ((const float*)src)[i];
}

// ---------------- weight transpose: (bf16|fp32)[R,C] @elem_off -> bf16 [C,R] ----------------
__global__ __launch_bounds__(256) void transpose_cvt_off(
    const void* __restrict__ src, size_t eoff, u16* __restrict__ dst,
    int R, int C, const uint32_t* __restrict__ flag) {
    __shared__ u16 tile[32][33];
    const bool isbf = (flag[0] != 0);
    int c0 = blockIdx.x * 32, r0 = blockIdx.y * 32;
    int tx = threadIdx.x & 31, ty = threadIdx.x >> 5;
#pragma unroll
    for (int j = 0; j < 32; j += 8) {
        size_t off = eoff + (size_t)(r0 + ty + j) * C + (c0 + tx);
        tile[ty + j][tx] = isbf ? ((const u16*)src)[off] : f2bf(((const float*)src)[off]);
    }
    __syncthreads();
#pragma unroll
    for (int j = 0; j < 32; j += 8)
        dst[(size_t)(c0 + ty + j) * R + (r0 + tx)] = tile[tx][ty + j];
}

// ---------------- LayerNorm: fp32 row(768) -> bf16 row ----------------
__global__ __launch_bounds__(256) void ln_kernel(
    const float* __restrict__ x, const float* __restrict__ g,
    const float* __restrict__ bta, u16* __restrict__ out) {
    int row = blockIdx.x, t = threadIdx.x;
    const float* xr = x + (size_t)row * Dc;
    float v0 = xr[t], v1 = xr[t + 256], v2 = xr[t + 512];
    float s = v0 + v1 + v2;
    float ss = v0 * v0 + v1 * v1 + v2 * v2;
    __shared__ float red[8];
    for (int m = 32; m; m >>= 1) { s += __shfl_xor(s, m, 64); ss += __shfl_xor(ss, m, 64); }
    int wave = t >> 6, lane = t & 63;
    if (lane == 0) { red[wave] = s; red[4 + wave] = ss; }
    __syncthreads();
    s  = red[0] + red[1] + red[2] + red[3];
    ss = red[4] + red[5] + red[6] + red[7];
    float mu = s * (1.0f / Dc);
    float var = ss * (1.0f / Dc) - mu * mu;
    float rs = rsqrtf(var + 1e-5f);
    u16* orow = out + (size_t)row * Dc;
    orow[t]       = f2bf((v0 - mu) * rs * g[t]       + bta[t]);
    orow[t + 256] = f2bf((v1 - mu) * rs * g[t + 256] + bta[t + 256]);
    orow[t + 512] = f2bf((v2 - mu) * rs * g[t + 512] + bta[t + 512]);
}

// ---------------- GEMM: A[M,K]bf16 @ Bt[N,K]bf16 -> epilogue ----------------
// m201 schedule with the CORRECT single-barrier phase (r4 post-mortem: the
// extra post-MFMA barrier forced CU-wide lockstep => LDS and MFMA pipes ran
// serially, 7750 cy/K-step vs ~3400 possible).
// 256x256 tile, BK=64, 512 threads = 8 waves (2M x 4N), 128x64 C per wave.
// LDS = [op 2][dbuf 2][khalf 2][256 x 32] = 128 KB; reads of step s hit
// dbuf[s&1]; stages during s fill dbuf[(s&1)^1] (units U1=A-k0,U2=B-k0,
// U3=A-k1,U4=B-k1, one per phase).
// Phase = { ds-reads ; STG ; [vmcnt(4) at P2,P4] ; s_barrier ;
//           lgkmcnt(0) ; sched_barrier ; setprio(1) 16 MFMA setprio(0) }
// NO barrier after the MFMA cluster: the next phase's reads issue right
// behind the MFMAs and drain in the LDS pipe underneath them (and under
// other waves' MFMAs) -- this inter-phase slack is the overlap mechanism.
// vmcnt gating (in-order retirement, 2 loads/unit, 8 in flight at each
// vmcnt): P2's vmcnt(4) retires U3,U4(prev) -> feeds P3,P4 reads; P4's
// vmcnt(4) retires U1,U2(next) -> feeds next P1,P2 reads. Both precede a
// barrier, publishing cross-wave. In-flight never <4, never drained to 0.
// Read-hoist safety: compiler may hoist a phase's reads at most to below
// the previous phase's lgkmcnt(0) asm-memory fence (sched_barrier pins the
// region), which is after the barrier that published their data -> safe.
// WAR: a stage unit overwrites a region whose last reads were drained by
// a lgkmcnt(0) a full K-step (4 barriers) earlier.
// Swizzle (0-conflict, r1-r4): within each 32-k half, 16B chunk at LDS pos
// p holds global chunk p ^ ((row>>1)&3); staged via pre-swizzled GLOBAL
// source (linear LDS dest keeps global_load_lds contiguity); reads XOR same.
// MODE 1: Cf = acc + bias[col] + res  (res may alias Cf, in-place residual)
// MODE 2: Cb = bf16(gelu(acc + bias[col]))
// MODE 3: Cb = bf16(acc), plus atomicAdd per-column sum of acc^2 into aux
// Requires: M%256==0, N%256==0, K%128==0.
template <int MODE>
__global__ __launch_bounds__(512, 2) void gemm_kernel(
    const u16* __restrict__ A, const u16* __restrict__ Bt,
    float* Cf, u16* Cb, const float* __restrict__ bias, const float* res,
    float* aux, int M, int N, int K) {
    __shared__ __attribute__((aligned(16))) u16 lds[2][2][2][256 * 32];
    const int tid = threadIdx.x;
    const int wave = tid >> 6, lane = tid & 63;
    const int wm = wave >> 2, wn = wave & 3;          // 2 x 4 wave grid
    const int bm = blockIdx.y * 256, bn = blockIdx.x * 256;
    const int NKS = K >> 6;                           // K-steps of 64 (even)

    u16* Lm = &lds[0][0][0][0];
    const u16* L = Lm;

    // ---- staging addressing: unit = 256 rows x 32 k; thread covers row
    // wave*16 + (lane>>2) (+128 for the 2nd load), chunk pos lane&3,
    // pre-swizzled global chunk:
    const int schunk = (lane & 3) ^ ((lane >> 3) & 3);
    const u16* ag = A  + (size_t)(bm + wave * 16 + (lane >> 2)) * K + schunk * 8;
    const u16* bg = Bt + (size_t)(bn + wave * 16 + (lane >> 2)) * K + schunk * 8;
    const size_t jstep = (size_t)128 * K;

    // ---- fragment read bases (u16 elems); swizzled chunk within k-half
    const int fm = lane & 15, fc = lane >> 4;
    const int chunk = (fc ^ ((fm >> 1) & 3)) * 8;
    const int aE0 = (wm * 128 + fm) * 32 + chunk;     // A, kh=0
    const int aE1 = 8192 + aE0;                       // A, kh=1
    const int bE0 = 32768 + (wn * 64 + fm) * 32 + chunk;
    const int bE1 = 8192 + bE0;

    f32x4 acc[8][4] = {};
    bf16x8 afr[8], bq[2], bq2[2];

#define STG(OP, GB, SS, DD, KH)                                              \
    {   const u16* g_ = GB + (size_t)(SS) * 64 + (KH) * 32;                  \
        u16* d_ = Lm + (OP) * 32768 + (DD) * 16384 + (KH) * 8192 + wave * 512; \
        ldg_lds16(g_, d_);                                                   \
        ldg_lds16(g_ + jstep, d_ + 4096); }

#define MF2(NB, BQ)                                                          \
    __builtin_amdgcn_s_setprio(1);                                           \
    _Pragma("unroll")                                                        \
    for (int m = 0; m < 8; ++m) {                                            \
        acc[m][(NB)]     = __builtin_amdgcn_mfma_f32_16x16x32_bf16(          \
            afr[m], BQ[0], acc[m][(NB)], 0, 0, 0);                           \
        acc[m][(NB) + 1] = __builtin_amdgcn_mfma_f32_16x16x32_bf16(          \
            afr[m], BQ[1], acc[m][(NB) + 1], 0, 0, 0);                       \
    }                                                                        \
    __builtin_amdgcn_s_setprio(0);

// single sync point per phase: barrier, then drain own ds_reads, then pin.
#define SYNC                                                                 \
    __builtin_amdgcn_s_barrier();                                            \
    asm volatile("s_waitcnt lgkmcnt(0)" ::: "memory");                       \
    __builtin_amdgcn_sched_barrier(0);

#define VM4 asm volatile("s_waitcnt vmcnt(4)" ::: "memory");

#define KSTEP(D, SS1) {                                                      \
    /* P1: reads A(kk0)x8 + B(kk0,nf01); stage U1=A-k0(s+1); MFMA kk0xnf01 */\
    _Pragma("unroll")                                                        \
    for (int m = 0; m < 8; ++m)                                              \
        afr[m] = *(const bf16x8*)(L + (D) * 16384 + aE0 + m * 512);          \
    bq[0] = *(const bf16x8*)(L + (D) * 16384 + bE0);                         \
    bq[1] = *(const bf16x8*)(L + (D) * 16384 + bE0 + 512);                   \
    STG(0, ag, SS1, (D) ^ 1, 0);                                             \
    SYNC;                                                                    \
    MF2(0, bq);                                                              \
    /* P2: reads B(kk0,nf23); stage U2=B-k0(s+1); vmcnt(4) retires U3,U4(s) */\
    bq2[0] = *(const bf16x8*)(L + (D) * 16384 + bE0 + 1024);                 \
    bq2[1] = *(const bf16x8*)(L + (D) * 16384 + bE0 + 1536);                 \
    STG(1, bg, SS1, (D) ^ 1, 0);                                             \
    VM4;                                                                     \
    SYNC;                                                                    \
    MF2(2, bq2);                                                             \
    /* P3: reads A(kk1)x8 + B(kk1,nf23); stage U3=A-k1(s+1); MFMA kk1xnf23 */\
    _Pragma("unroll")                                                        \
    for (int m = 0; m < 8; ++m)                                              \
        afr[m] = *(const bf16x8*)(L + (D) * 16384 + aE1 + m * 512);          \
    bq2[0] = *(const bf16x8*)(L + (D) * 16384 + bE1 + 1024);                 \
    bq2[1] = *(const bf16x8*)(L + (D) * 16384 + bE1 + 1536);                 \
    STG(0, ag, SS1, (D) ^ 1, 1);                                             \
    SYNC;                                                                    \
    MF2(2, bq2);                                                             \
    /* P4: reads B(kk1,nf01); stage U4=B-k1(s+1); vmcnt(4) retires U1,U2(s+1) */\
    bq[0] = *(const bf16x8*)(L + (D) * 16384 + bE1);                         \
    bq[1] = *(const bf16x8*)(L + (D) * 16384 + bE1 + 512);                   \
    STG(1, bg, SS1, (D) ^ 1, 1);                                             \
    VM4;                                                                     \
    SYNC;                                                                    \
    MF2(0, bq);                                                              \
}

    // ---- prologue: stage K-step 0 (U1..U4 into dbuf0); U1,U2 must land.
    STG(0, ag, 0, 0, 0);
    STG(1, bg, 0, 0, 0);
    STG(0, ag, 0, 0, 1);
    STG(1, bg, 0, 0, 1);
    asm volatile("s_waitcnt vmcnt(4)" ::: "memory");   // U1,U2(0) landed
    __builtin_amdgcn_s_barrier();
    __builtin_amdgcn_sched_barrier(0);

    for (int s = 0; s < NKS; s += 2) {
        KSTEP(0, s + 1);
        const int s2 = (s + 2 < NKS) ? s + 2 : 0;      // tail: garbage into dead slot
        KSTEP(1, s2);
    }
    // drain clamped tail stages before LDS dealloc at kernel end
    asm volatile("s_waitcnt vmcnt(0)" ::: "memory");

#undef KSTEP
#undef VM4
#undef SYNC
#undef MF2
#undef STG

    // epilogue: C/D layout col=lane&15, row=(lane>>4)*4+reg  [m89/m91]
    const int er = (lane >> 4) * 4;
    const int ec = lane & 15;
    float csq[4] = {0.f, 0.f, 0.f, 0.f};
#pragma unroll
    for (int mf = 0; mf < 8; ++mf) {
        const int row0 = bm + wm * 128 + mf * 16 + er;
#pragma unroll
        for (int nf = 0; nf < 4; ++nf) {
            const int col = bn + wn * 64 + nf * 16 + ec;
#pragma unroll
            for (int r = 0; r < 4; ++r) {
                const size_t off = (size_t)(row0 + r) * N + col;
                float v = acc[mf][nf][r];
                if (MODE == 1) {
                    Cf[off] = v + bias[col] + res[off];
                } else if (MODE == 2) {
                    Cb[off] = f2bf(gelu_fast(v + bias[col]));
                } else { // MODE 3
                    Cb[off] = f2bf(v);
                    csq[nf] += v * v;
                }
            }
        }
    }
    if (MODE == 3) {
        const int b = bm >> 12;                    // 256-row tile sits in one batch
#pragma unroll
        for (int nf = 0; nf < 4; ++nf) {
            float s = csq[nf];
            s += __shfl_xor(s, 16, 64);
            s += __shfl_xor(s, 32, 64);
            if (lane < 16) {
                const int col = bn + wn * 64 + nf * 16 + lane;
                const int bh = b * Hc + (col >> 6);
                atomicAdd(&aux[bh * DHc + (col & 63)], s);
            }
        }
    }
}

// ---------------- attention statistics (w is bf16 now) ----------------
// logits[b,h,n] = temp[h] * sum_d w^2 / max(nrm2,1e-24); block 256=(dq 0..3, nr 0..63)
__global__ __launch_bounds__(256) void logits_kernel(
    const u16* __restrict__ w, const float* __restrict__ nrm2,
    const float* __restrict__ tp, float* __restrict__ logits) {
    int blk = blockIdx.x;
    int chunk = blk & 15, bh = blk >> 4;
    int b = bh / Hc, h = bh - b * Hc;
    int t = threadIdx.x, dq = t & 3, nr = t >> 2;
    __shared__ float inv[64];
    if (t < 64) inv[t] = 1.0f / fmaxf(nrm2[bh * DHc + t], 1e-24f);
    __syncthreads();
    float tl = tp[h];
#pragma unroll
    for (int jj = 0; jj < 4; jj++) {
        int n = chunk * 256 + jj * 64 + nr;
        const uint4* wr = (const uint4*)(w + ((size_t)b * Nc + n) * Dc + h * DHc + dq * 16);
        uint4 u0 = wr[0], u1 = wr[1];
        float acc = 0.f;
        float e0, e1;
        const float* iv = inv + dq * 16;
        unp2(u0.x, e0, e1); acc += e0 * e0 * iv[0]  + e1 * e1 * iv[1];
        unp2(u0.y, e0, e1); acc += e0 * e0 * iv[2]  + e1 * e1 * iv[3];
        unp2(u0.z, e0, e1); acc += e0 * e0 * iv[4]  + e1 * e1 * iv[5];
        unp2(u0.w, e0, e1); acc += e0 * e0 * iv[6]  + e1 * e1 * iv[7];
        unp2(u1.x, e0, e1); acc += e0 * e0 * iv[8]  + e1 * e1 * iv[9];
        unp2(u1.y, e0, e1); acc += e0 * e0 * iv[10] + e1 * e1 * iv[11];
        unp2(u1.z, e0, e1); acc += e0 * e0 * iv[12] + e1 * e1 * iv[13];
        unp2(u1.w, e0, e1); acc += e0 * e0 * iv[14] + e1 * e1 * iv[15];
        acc += __shfl_xor(acc, 1, 64);
        acc += __shfl_xor(acc, 2, 64);
        if (dq == 0) logits[(size_t)bh * Nc + n] = tl * acc;
    }
}

__global__ __launch_bounds__(256) void softmax_kernel(
    const float* __restrict__ logits, float* __restrict__ Pi, float* __restrict__ rowsc) {
    int bh = blockIdx.x, t = threadIdx.x;
    int wave = t >> 6, lane = t & 63;
    const float4* lg = (const float4*)(logits + (size_t)bh * Nc);
    float4 v[4];
    float mx = -3.4e38f;
    __shared__ float red[4];
#pragma unroll
    for (int j = 0; j < 4; j++) {
        v[j] = lg[t + 256 * j];
        mx = fmaxf(mx, fmaxf(fmaxf(v[j].x, v[j].y), fmaxf(v[j].z, v[j].w)));
    }
    for (int m = 32; m; m >>= 1) mx = fmaxf(mx, __shfl_xor(mx, m, 64));
    if (lane == 0) red[wave] = mx;
    __syncthreads();
    mx = fmaxf(fmaxf(red[0], red[1]), fmaxf(red[2], red[3]));
    __syncthreads();
    float s = 0.f;
#pragma unroll
    for (int j = 0; j < 4; j++) {
        v[j].x = expf(v[j].x - mx); v[j].y = expf(v[j].y - mx);
        v[j].z = expf(v[j].z - mx); v[j].w = expf(v[j].w - mx);
        s += v[j].x + v[j].y + v[j].z + v[j].w;
    }
    for (int m = 32; m; m >>= 1) s += __shfl_xor(s, m, 64);
    if (lane == 0) red[wave] = s;
    __syncthreads();
    s = red[0] + red[1] + red[2] + red[3];
    __syncthreads();
    float invs = 1.0f / s;
    float s2 = 0.f;
    float4* Pr = (float4*)(Pi + (size_t)bh * Nc);
#pragma unroll
    for (int j = 0; j < 4; j++) {
        float4 p;
        p.x = v[j].x * invs; p.y = v[j].y * invs;
        p.z = v[j].z * invs; p.w = v[j].w * invs;
        s2 += p.x + p.y + p.z + p.w;
        Pr[t + 256 * j] = p;
    }
    for (int m = 32; m; m >>= 1) s2 += __shfl_xor(s2, m, 64);
    if (lane == 0) red[wave] = s2;
    __syncthreads();
    if (t == 0) rowsc[bh] = 1.0f / (red[0] + red[1] + red[2] + red[3] + 1e-8f);
}

// dots[b,h,d] = sum_n Pi_n * w^2 ; w bf16, vectorized uint2 (4 bf16) per lane
__global__ __launch_bounds__(256) void dots_kernel(
    const u16* __restrict__ w, const float* __restrict__ Pi,
    const float* __restrict__ rowsc, float* __restrict__ dots) {
    int blk = blockIdx.x;
    int chunk = blk & 15, bh = blk >> 4;
    int b = bh / Hc, h = bh - b * Hc;
    int t = threadIdx.x, d4 = t & 15, rg = t >> 4;
    const u16* base = w + ((size_t)b * Nc + chunk * 256 + rg) * Dc + h * DHc + d4 * 4;
    const float* Prow = Pi + (size_t)bh * Nc + chunk * 256 + rg;
    float4 acc = {0.f, 0.f, 0.f, 0.f};
#pragma unroll 4
    for (int j = 0; j < 16; j++) {
        uint2 u = *(const uint2*)(base + (size_t)j * 16 * Dc);
        float p = Prow[j * 16];
        float a0, a1, a2, a3;
        unp2(u.x, a0, a1); unp2(u.y, a2, a3);
        acc.x += p * a0 * a0; acc.y += p * a1 * a1;
        acc.z += p * a2 * a2; acc.w += p * a3 * a3;
    }
    __shared__ float4 red[256];
    red[t] = acc;
    __syncthreads();
    if (t < 64) {
        float s = 0.f;
#pragma unroll
        for (int r = 0; r < 16; r++) {
            const float* f = (const float*)&red[r * 16 + (t >> 2)];
            s += f[t & 3];
        }
        atomicAdd(&dots[bh * DHc + t], s * rowsc[bh]);
    }
}

// attn-out: abuf = bf16( -(w*Pi) / (1+dots) ); 8 bf16 per thread
__global__ __launch_bounds__(256) void attnout_kernel(
    const u16* __restrict__ w, const float* __restrict__ Pi,
    const float* __restrict__ dots, u16* __restrict__ out) {
    int idx = blockIdx.x * 256 + threadIdx.x;       // uint4 index < Mc*Dc/8
    int cg = idx % (Dc / 8);
    int m = idx / (Dc / 8);
    int b = m >> 12, n = m & 4095;
    int c = cg * 8, h = c >> 6, d = c & 63;
    int bh = b * Hc + h;
    uint4 wv = ((const uint4*)w)[idx];
    float pi = Pi[(size_t)bh * Nc + n];
    float4 dv0 = *(const float4*)(dots + bh * DHc + d);
    float4 dv1 = *(const float4*)(dots + bh * DHc + d + 4);
    float a0, a1, a2, a3, a4, a5, a6, a7;
    unp2(wv.x, a0, a1); unp2(wv.y, a2, a3);
    unp2(wv.z, a4, a5); unp2(wv.w, a6, a7);
    union { u16 u[8]; uint4 v4; } pk;
    pk.u[0] = f2bf(-(a0 * pi) / (1.0f + dv0.x));
    pk.u[1] = f2bf(-(a1 * pi) / (1.0f + dv0.y));
    pk.u[2] = f2bf(-(a2 * pi) / (1.0f + dv0.z));
    pk.u[3] = f2bf(-(a3 * pi) / (1.0f + dv0.w));
    pk.u[4] = f2bf(-(a4 * pi) / (1.0f + dv1.x));
    pk.u[5] = f2bf(-(a5 * pi) / (1.0f + dv1.y));
    pk.u[6] = f2bf(-(a6 * pi) / (1.0f + dv1.z));
    pk.u[7] = f2bf(-(a7 * pi) / (1.0f + dv1.w));
    ((uint4*)out)[idx] = pk.v4;
}

// ---------------- host-side launch ----------------
extern "C" void kernel_launch(void* const* d_in, const int* in_sizes, int n_in,
                              void* d_out, int out_size, void* d_ws, size_t ws_size,
                              hipStream_t stream) {
    const void* x_in = d_in[0];
    const void* ln1g = d_in[1];
    const void* ln1b = d_in[2];
    const void* qkvw = d_in[3];
    const void* temp = d_in[4];
    const void* outw = d_in[5];
    const void* outb = d_in[6];
    const void* ln2g = d_in[7];
    const void* ln2b = d_in[8];
    const void* fc1w = d_in[9];
    const void* fc1b = d_in[10];
    const void* fc2w = d_in[11];
    const void* fc2b = d_in[12];

    char* p = (char*)d_ws;
    auto alloc = [&](size_t bytes) {
        void* r = (void*)p;
        p += (bytes + 255) & ~(size_t)255;
        return r;
    };
    float* xbuf = (float*)alloc((size_t)Mc * Dc * 4);        // 50.3 MB residual (fp32)
    void*  big  = alloc((size_t)Mc * HIDc * 2);              // 100.7 MB union region
    u16*   wbuf = (u16*)big;                                 //   bf16 [M,D] qkv output
    u16*   gbuf = (u16*)big;                                 //   bf16 [M,HID] gelu output
    u16*  abuf  = (u16*)alloc((size_t)Mc * Dc * 2);          // 25.2 MB bf16 activations
    const size_t QKV_T = (size_t)Dc * Dc, OUT_T = (size_t)Dc * Dc;
    const size_t FC1_T = (size_t)HIDc * Dc, FC2_T = (size_t)Dc * HIDc;
    const size_t LSTRIDE = QKV_T + OUT_T + FC1_T + FC2_T;
    u16*  wTL   = (u16*)alloc(LSTRIDE * 2);                  // 11.8 MB per-layer weightsT
    float* nrm2 = (float*)alloc((size_t)BHDc * 4);
    float* dots = (float*)alloc((size_t)BHDc * 4);           // contiguous after nrm2
    float* logit = (float*)alloc((size_t)BHc * Nc * 4);
    float* Pi    = (float*)alloc((size_t)BHc * Nc * 4);
    float* rowsc = (float*)alloc((size_t)BHc * 4);
    uint32_t* flag = (uint32_t*)alloc(256);
    float* ln1g_f = (float*)alloc((size_t)DEPTHc * Dc * 4);
    float* ln1b_f = (float*)alloc((size_t)DEPTHc * Dc * 4);
    float* ln2g_f = (float*)alloc((size_t)DEPTHc * Dc * 4);
    float* ln2b_f = (float*)alloc((size_t)DEPTHc * Dc * 4);
    float* outb_f = (float*)alloc((size_t)DEPTHc * Dc * 4);
    float* fc1b_f = (float*)alloc((size_t)DEPTHc * HIDc * 4);
    float* fc2b_f = (float*)alloc((size_t)DEPTHc * Dc * 4);
    float* temp_f = (float*)alloc((size_t)DEPTHc * Hc * 4);
    if ((size_t)(p - (char*)d_ws) > ws_size) {
        sentinel_kernel<<<(out_size + 255) / 256, 256, 0, stream>>>((u16*)d_out, out_size);
        return;
    }

    detect_kernel<<<1, 256, 0, stream>>>((const uint32_t*)x_in, flag);

    auto cvt = [&](const void* s, float* d, int n) {
        cvt_param_kernel<<<(n + 255) / 256, 256, 0, stream>>>(s, d, n, flag);
    };
    cvt(x_in, xbuf, Mc * Dc);
    cvt(ln1g, ln1g_f, DEPTHc * Dc);
    cvt(ln1b, ln1b_f, DEPTHc * Dc);
    cvt(ln2g, ln2g_f, DEPTHc * Dc);
    cvt(ln2b, ln2b_f, DEPTHc * Dc);
    cvt(outb, outb_f, DEPTHc * Dc);
    cvt(fc1b, fc1b_f, DEPTHc * HIDc);
    cvt(fc2b, fc2b_f, DEPTHc * Dc);
    cvt(temp, temp_f, DEPTHc * Hc);

    u16* qkvT = wTL;
    u16* outT = qkvT + QKV_T;
    u16* fc1T = outT + OUT_T;
    u16* fc2T = fc1T + FC1_T;

    for (int i = 0; i < DEPTHc; i++) {
        transpose_cvt_off<<<dim3(Dc / 32, Dc / 32), 256, 0, stream>>>(
            qkvw, (size_t)i * Dc * Dc, qkvT, Dc, Dc, flag);
        transpose_cvt_off<<<dim3(Dc / 32, Dc / 32), 256, 0, stream>>>(
            outw, (size_t)i * Dc * Dc, outT, Dc, Dc, flag);
        transpose_cvt_off<<<dim3(HIDc / 32, Dc / 32), 256, 0, stream>>>(
            fc1w, (size_t)i * Dc * HIDc, fc1T, Dc, HIDc, flag);
        transpose_cvt_off<<<dim3(Dc / 32, HIDc / 32), 256, 0, stream>>>(
            fc2w, (size_t)i * HIDc * Dc, fc2T, HIDc, Dc, flag);

        // h = LN1(x) -> bf16
        ln_kernel<<<Mc, 256, 0, stream>>>(xbuf, ln1g_f + i * Dc, ln1b_f + i * Dc, abuf);
        // zero nrm2+dots BEFORE qkv gemm (its epilogue accumulates nrm2)
        hipMemsetAsync(nrm2, 0, (size_t)2 * BHDc * 4, stream);
        // w = h @ qkv_w -> bf16 wbuf, fused column-sumsq into nrm2
        gemm_kernel<3><<<dim3(Dc / 256, Mc / 256), 512, 0, stream>>>(
            abuf, qkvT, nullptr, wbuf, nullptr, nullptr, nrm2, Mc, Dc, Dc);
        logits_kernel<<<BHc * 16, 256, 0, stream>>>(wbuf, nrm2, temp_f + i * Hc, logit);
        softmax_kernel<<<BHc, 256, 0, stream>>>(logit, Pi, rowsc);
        dots_kernel<<<BHc * 16, 256, 0, stream>>>(wbuf, Pi, rowsc, dots);
        attnout_kernel<<<(Mc * Dc / 8) / 256, 256, 0, stream>>>(wbuf, Pi, dots, abuf);
        // x = attnout @ out_w + out_b + x
        gemm_kernel<1><<<dim3(Dc / 256, Mc / 256), 512, 0, stream>>>(
            abuf, outT, xbuf, nullptr, outb_f + i * Dc, xbuf, nullptr, Mc, Dc, Dc);
        // h2 = LN2(x) -> bf16
        ln_kernel<<<Mc, 256, 0, stream>>>(xbuf, ln2g_f + i * Dc, ln2b_f + i * Dc, abuf);
        // g = gelu(h2 @ fc1_w + fc1_b) -> bf16 (union region; wbuf dead now)
        gemm_kernel<2><<<dim3(HIDc / 256, Mc / 256), 512, 0, stream>>>(
            abuf, fc1T, nullptr, gbuf, fc1b_f + i * HIDc, nullptr, nullptr, Mc, HIDc, Dc);
        // x = g @ fc2_w + fc2_b + x
        gemm_kernel<1><<<dim3(Dc / 256, Mc / 256), 512, 0, stream>>>(
            gbuf, fc2T, xbuf, nullptr, fc2b_f + i * Dc, xbuf, nullptr, Mc, Dc, HIDc);
    }
    hipMemcpyAsync(d_out, xbuf, (size_t)Mc * Dc * 4, hipMemcpyDeviceToDevice, stream);
}

// Round 6
// 1639.704 us; speedup vs baseline: 1.0444x; 1.0444x over previous
//
#include <hip/hip_runtime.h>
#include <cstdint>
#include <cstddef>

// ---------------- problem constants ----------------
static constexpr int Bc = 4, Nc = 4096, Dc = 768, Hc = 12, DHc = 64;
static constexpr int HIDc = 3072, DEPTHc = 4;
static constexpr int Mc = Bc * Nc;        // 16384 rows
static constexpr int BHc = Bc * Hc;       // 48
static constexpr int BHDc = BHc * DHc;    // 3072

typedef unsigned short u16;
typedef __bf16 bf16x8 __attribute__((ext_vector_type(8)));
typedef float  f32x4  __attribute__((ext_vector_type(4)));

#define DEV __device__ __forceinline__

DEV u16 f2bf(float x) {            // RNE float->bf16
    uint32_t u = __float_as_uint(x);
    u += 0x7fffu + ((u >> 16) & 1u);
    return (u16)(u >> 16);
}
DEV float bf2f(u16 u) { return __uint_as_float(((uint32_t)u) << 16); }
DEV void unp2(uint32_t u, float& a, float& b) {   // packed bf16 pair -> 2 fp32
    a = __uint_as_float(u << 16);
    b = __uint_as_float(u & 0xffff0000u);
}
DEV float gelu_fast(float x) {     // tanh-form GELU, |err|<3e-3 vs exact erf form
    float y = 0.7978845608f * (x + 0.044715f * x * x * x);
    float e = __expf(2.0f * y);
    float t = 1.0f - 2.0f / (e + 1.0f);
    return 0.5f * x * (1.0f + t);
}

// global -> LDS direct (16B per lane). LDS dest = wave-uniform base + lane*16.
DEV void ldg_lds16(const void* g, void* l) {
    __builtin_amdgcn_global_load_lds(
        (const __attribute__((address_space(1))) uint32_t*)(uintptr_t)g,
        (__attribute__((address_space(3))) uint32_t*)(uint32_t)(uintptr_t)l,
        16, 0, 0);
}

// ---------------- input dtype sniffer (robustness; measured: fp32) ----------------
__global__ void detect_kernel(const uint32_t* __restrict__ x, uint32_t* __restrict__ flag) {
    int t = threadIdx.x;
    uint32_t w = x[t];
    int e = (w >> 7) & 0xFF;
    __shared__ int cnt[256];
    cnt[t] = (e >= 100 && e <= 140) ? 1 : 0;
    __syncthreads();
    for (int s = 128; s; s >>= 1) {
        if (t < s) cnt[t] += cnt[t + s];
        __syncthreads();
    }
    if (t == 0) flag[0] = (cnt[0] >= 128) ? 1u : 0u;
}

// sentinel: absmax ~1234 == "workspace too small"
__global__ __launch_bounds__(256) void sentinel_kernel(u16* __restrict__ out, int n) {
    int i = blockIdx.x * 256 + threadIdx.x;
    if (i < n) out[i] = 0x449A;
}

__global__ __launch_bounds__(256) void cvt_param_kernel(
    const void* __restrict__ src, float* __restrict__ dst, int n,
    const uint32_t* __restrict__ flag) {
    int i = blockIdx.x * 256 + threadIdx.x;
    if (i >= n) return;
    if (flag[0]) dst[i] = bf2f(((const u16*)src)[i]);
    else         dst[i] = ((const float*)src)[i];
}

// ---------------- weight transpose: (bf16|fp32)[R,C] @elem_off -> bf16 [C,R] ----------------
__global__ __launch_bounds__(256) void transpose_cvt_off(
    const void* __restrict__ src, size_t eoff, u16* __restrict__ dst,
    int R, int C, const uint32_t* __restrict__ flag) {
    __shared__ u16 tile[32][33];
    const bool isbf = (flag[0] != 0);
    int c0 = blockIdx.x * 32, r0 = blockIdx.y * 32;
    int tx = threadIdx.x & 31, ty = threadIdx.x >> 5;
#pragma unroll
    for (int j = 0; j < 32; j += 8) {
        size_t off = eoff + (size_t)(r0 + ty + j) * C + (c0 + tx);
        tile[ty + j][tx] = isbf ? ((const u16*)src)[off] : f2bf(((const float*)src)[off]);
    }
    __syncthreads();
#pragma unroll
    for (int j = 0; j < 32; j += 8)
        dst[(size_t)(c0 + ty + j) * R + (r0 + tx)] = tile[tx][ty + j];
}

// ---------------- LayerNorm: fp32 row(768) -> bf16 row ----------------
__global__ __launch_bounds__(256) void ln_kernel(
    const float* __restrict__ x, const float* __restrict__ g,
    const float* __restrict__ bta, u16* __restrict__ out) {
    int row = blockIdx.x, t = threadIdx.x;
    const float* xr = x + (size_t)row * Dc;
    float v0 = xr[t], v1 = xr[t + 256], v2 = xr[t + 512];
    float s = v0 + v1 + v2;
    float ss = v0 * v0 + v1 * v1 + v2 * v2;
    __shared__ float red[8];
    for (int m = 32; m; m >>= 1) { s += __shfl_xor(s, m, 64); ss += __shfl_xor(ss, m, 64); }
    int wave = t >> 6, lane = t & 63;
    if (lane == 0) { red[wave] = s; red[4 + wave] = ss; }
    __syncthreads();
    s  = red[0] + red[1] + red[2] + red[3];
    ss = red[4] + red[5] + red[6] + red[7];
    float mu = s * (1.0f / Dc);
    float var = ss * (1.0f / Dc) - mu * mu;
    float rs = rsqrtf(var + 1e-5f);
    u16* orow = out + (size_t)row * Dc;
    orow[t]       = f2bf((v0 - mu) * rs * g[t]       + bta[t]);
    orow[t + 256] = f2bf((v1 - mu) * rs * g[t + 256] + bta[t + 256]);
    orow[t + 512] = f2bf((v2 - mu) * rs * g[t + 512] + bta[t + 512]);
}

// ---------------- GEMM: A[M,K]bf16 @ Bt[N,K]bf16 -> epilogue ----------------
// LEAN schedule (r5 post-mortem): persistent frag arrays + sched_barrier
// pinning in r2-r5 generated ~55us/dispatch of VALU register-marshalling
// that saturated the wave issue slot (r1 without them: 15us). This version
// has NO persistent frag arrays, NO sched_barrier, NO lgkm asm, NO setprio:
// short-lived locals per sub-phase; the compiler emits its own fine-grained
// counted lgkmcnt between ds_read and consuming MFMA (m97 asm evidence) and
// interleaves them optimally. Only counted vmcnt + raw s_barrier survive.
// 256x256 tile, BK=64, 512 threads = 8 waves (2M x 4N), 128x64 C per wave.
// LDS = [op 2][dbuf 2][khalf 2][256 x 32] = 128 KB; step s reads dbuf[s&1],
// stages step s+1 into dbuf[(s&1)^1], one k-half (A+B, 4 loads) per sub-phase.
// Per K-step: 2 sub-phases (kk0,kk1), each:
//   { 12 ds_reads (8 A + 4 B, locals) ; 4 global_load_lds ;
//     16x2 MFMA ; asm vmcnt(4) ; s_barrier }
// vmcnt gating (in-order retirement): at end of (s,kk0), in flight =
// {(s+1,kh0)[4], (s,kh1)[4]} -> vmcnt(4) retires (s,kh1), exactly what kk1
// reads; at end of (s,kk1), in flight = {(s+1,kh1),(s+1,kh0)} -> retires
// (s+1,kh0) for the next kk0. Never drained below 4 in the loop. Each vmcnt
// immediately precedes its barrier (publishes cross-wave); the asm memory
// clobber stops post-barrier ds_reads hoisting across.
// WAR: stage into dbuf D^1 is issued after the barrier; all waves' reads of
// D^1 completed before their pre-barrier MFMAs (compiler lgkm data deps).
// Swizzle (0-conflict r1-r5): 16B chunk at LDS pos p holds global chunk
// p ^ ((row>>1)&3), staged via pre-swizzled GLOBAL source (linear LDS dest).
// MODE 1: Cf = acc + bias[col] + res  (res may alias Cf, in-place residual)
// MODE 2: Cb = bf16(gelu(acc + bias[col]))
// MODE 3: Cb = bf16(acc), plus atomicAdd per-column sum of acc^2 into aux
// Requires: M%256==0, N%256==0, K%128==0.
template <int MODE>
__global__ __launch_bounds__(512, 2) void gemm_kernel(
    const u16* __restrict__ A, const u16* __restrict__ Bt,
    float* Cf, u16* Cb, const float* __restrict__ bias, const float* res,
    float* aux, int M, int N, int K) {
    __shared__ __attribute__((aligned(16))) u16 lds[2][2][2][256 * 32];
    const int tid = threadIdx.x;
    const int wave = tid >> 6, lane = tid & 63;
    const int wm = wave >> 2, wn = wave & 3;          // 2 x 4 wave grid
    const int bm = blockIdx.y * 256, bn = blockIdx.x * 256;
    const int NKS = K >> 6;                           // K-steps of 64 (even)

    u16* Lm = &lds[0][0][0][0];
    const u16* L = Lm;

    // ---- staging addressing: unit = 256 rows x 32 k (one op, one k-half);
    // thread covers row wave*16 + (lane>>2) (+128 for 2nd load), chunk pos
    // lane&3, pre-swizzled global chunk:
    const int schunk = (lane & 3) ^ ((lane >> 3) & 3);
    const u16* ag = A  + (size_t)(bm + wave * 16 + (lane >> 2)) * K + schunk * 8;
    const u16* bg = Bt + (size_t)(bn + wave * 16 + (lane >> 2)) * K + schunk * 8;
    const size_t jstep = (size_t)128 * K;

    // ---- fragment read bases (u16 elems); swizzled chunk within k-half
    const int fm = lane & 15, fc = lane >> 4;
    const int chunk = (fc ^ ((fm >> 1) & 3)) * 8;
    const int aE0 = (wm * 128 + fm) * 32 + chunk;     // A, kh=0
    const int aE1 = 8192 + aE0;                       // A, kh=1
    const int bE0 = 32768 + (wn * 64 + fm) * 32 + chunk;
    const int bE1 = 8192 + bE0;

    f32x4 acc[8][4] = {};

#define STG(OP, GB, SS, DD, KH)                                              \
    {   const u16* g_ = GB + (size_t)(SS) * 64 + (KH) * 32;                  \
        u16* d_ = Lm + (OP) * 32768 + (DD) * 16384 + (KH) * 8192 + wave * 512; \
        ldg_lds16(g_, d_);                                                   \
        ldg_lds16(g_ + jstep, d_ + 4096); }

#define SUBPHASE(D, AE, BE, S1, KH) {                                        \
    bf16x8 af_[8], b_[4];                                                    \
    _Pragma("unroll")                                                        \
    for (int m = 0; m < 8; ++m)                                              \
        af_[m] = *(const bf16x8*)(L + (D) * 16384 + (AE) + m * 512);         \
    _Pragma("unroll")                                                        \
    for (int n = 0; n < 4; ++n)                                              \
        b_[n] = *(const bf16x8*)(L + (D) * 16384 + (BE) + n * 512);          \
    STG(0, ag, S1, (D) ^ 1, KH);                                             \
    STG(1, bg, S1, (D) ^ 1, KH);                                             \
    _Pragma("unroll")                                                        \
    for (int m = 0; m < 8; ++m) {                                            \
        acc[m][0] = __builtin_amdgcn_mfma_f32_16x16x32_bf16(af_[m], b_[0], acc[m][0], 0, 0, 0); \
        acc[m][1] = __builtin_amdgcn_mfma_f32_16x16x32_bf16(af_[m], b_[1], acc[m][1], 0, 0, 0); \
        acc[m][2] = __builtin_amdgcn_mfma_f32_16x16x32_bf16(af_[m], b_[2], acc[m][2], 0, 0, 0); \
        acc[m][3] = __builtin_amdgcn_mfma_f32_16x16x32_bf16(af_[m], b_[3], acc[m][3], 0, 0, 0); \
    }                                                                        \
    asm volatile("s_waitcnt vmcnt(4)" ::: "memory");                         \
    __builtin_amdgcn_s_barrier();                                            \
}

#define KSTEP(D, S1)                                                         \
    SUBPHASE(D, aE0, bE0, S1, 0);                                            \
    SUBPHASE(D, aE1, bE1, S1, 1);

    // ---- prologue: stage K-step 0 (kh0 then kh1); kh0 must land.
    STG(0, ag, 0, 0, 0);
    STG(1, bg, 0, 0, 0);
    STG(0, ag, 0, 0, 1);
    STG(1, bg, 0, 0, 1);
    asm volatile("s_waitcnt vmcnt(4)" ::: "memory");   // kh0(0) landed
    __builtin_amdgcn_s_barrier();

    for (int s = 0; s < NKS; s += 2) {
        KSTEP(0, s + 1);
        const int s2 = (s + 2 < NKS) ? s + 2 : 0;      // tail: garbage to dead dbuf
        KSTEP(1, s2);
    }
    // drain clamped tail stages before kernel end
    asm volatile("s_waitcnt vmcnt(0)" ::: "memory");

#undef KSTEP
#undef SUBPHASE
#undef STG

    // epilogue: C/D layout col=lane&15, row=(lane>>4)*4+reg  [m89/m91]
    const int er = (lane >> 4) * 4;
    const int ec = lane & 15;
    float csq[4] = {0.f, 0.f, 0.f, 0.f};
#pragma unroll
    for (int mf = 0; mf < 8; ++mf) {
        const int row0 = bm + wm * 128 + mf * 16 + er;
#pragma unroll
        for (int nf = 0; nf < 4; ++nf) {
            const int col = bn + wn * 64 + nf * 16 + ec;
#pragma unroll
            for (int r = 0; r < 4; ++r) {
                const size_t off = (size_t)(row0 + r) * N + col;
                float v = acc[mf][nf][r];
                if (MODE == 1) {
                    Cf[off] = v + bias[col] + res[off];
                } else if (MODE == 2) {
                    Cb[off] = f2bf(gelu_fast(v + bias[col]));
                } else { // MODE 3
                    Cb[off] = f2bf(v);
                    csq[nf] += v * v;
                }
            }
        }
    }
    if (MODE == 3) {
        const int b = bm >> 12;                    // 256-row tile sits in one batch
#pragma unroll
        for (int nf = 0; nf < 4; ++nf) {
            float s = csq[nf];
            s += __shfl_xor(s, 16, 64);
            s += __shfl_xor(s, 32, 64);
            if (lane < 16) {
                const int col = bn + wn * 64 + nf * 16 + lane;
                const int bh = b * Hc + (col >> 6);
                atomicAdd(&aux[bh * DHc + (col & 63)], s);
            }
        }
    }
}

// ---------------- attention statistics (w is bf16 now) ----------------
// logits[b,h,n] = temp[h] * sum_d w^2 / max(nrm2,1e-24); block 256=(dq 0..3, nr 0..63)
__global__ __launch_bounds__(256) void logits_kernel(
    const u16* __restrict__ w, const float* __restrict__ nrm2,
    const float* __restrict__ tp, float* __restrict__ logits) {
    int blk = blockIdx.x;
    int chunk = blk & 15, bh = blk >> 4;
    int b = bh / Hc, h = bh - b * Hc;
    int t = threadIdx.x, dq = t & 3, nr = t >> 2;
    __shared__ float inv[64];
    if (t < 64) inv[t] = 1.0f / fmaxf(nrm2[bh * DHc + t], 1e-24f);
    __syncthreads();
    float tl = tp[h];
#pragma unroll
    for (int jj = 0; jj < 4; jj++) {
        int n = chunk * 256 + jj * 64 + nr;
        const uint4* wr = (const uint4*)(w + ((size_t)b * Nc + n) * Dc + h * DHc + dq * 16);
        uint4 u0 = wr[0], u1 = wr[1];
        float acc = 0.f;
        float e0, e1;
        const float* iv = inv + dq * 16;
        unp2(u0.x, e0, e1); acc += e0 * e0 * iv[0]  + e1 * e1 * iv[1];
        unp2(u0.y, e0, e1); acc += e0 * e0 * iv[2]  + e1 * e1 * iv[3];
        unp2(u0.z, e0, e1); acc += e0 * e0 * iv[4]  + e1 * e1 * iv[5];
        unp2(u0.w, e0, e1); acc += e0 * e0 * iv[6]  + e1 * e1 * iv[7];
        unp2(u1.x, e0, e1); acc += e0 * e0 * iv[8]  + e1 * e1 * iv[9];
        unp2(u1.y, e0, e1); acc += e0 * e0 * iv[10] + e1 * e1 * iv[11];
        unp2(u1.z, e0, e1); acc += e0 * e0 * iv[12] + e1 * e1 * iv[13];
        unp2(u1.w, e0, e1); acc += e0 * e0 * iv[14] + e1 * e1 * iv[15];
        acc += __shfl_xor(acc, 1, 64);
        acc += __shfl_xor(acc, 2, 64);
        if (dq == 0) logits[(size_t)bh * Nc + n] = tl * acc;
    }
}

__global__ __launch_bounds__(256) void softmax_kernel(
    const float* __restrict__ logits, float* __restrict__ Pi, float* __restrict__ rowsc) {
    int bh = blockIdx.x, t = threadIdx.x;
    int wave = t >> 6, lane = t & 63;
    const float4* lg = (const float4*)(logits + (size_t)bh * Nc);
    float4 v[4];
    float mx = -3.4e38f;
    __shared__ float red[4];
#pragma unroll
    for (int j = 0; j < 4; j++) {
        v[j] = lg[t + 256 * j];
        mx = fmaxf(mx, fmaxf(fmaxf(v[j].x, v[j].y), fmaxf(v[j].z, v[j].w)));
    }
    for (int m = 32; m; m >>= 1) mx = fmaxf(mx, __shfl_xor(mx, m, 64));
    if (lane == 0) red[wave] = mx;
    __syncthreads();
    mx = fmaxf(fmaxf(red[0], red[1]), fmaxf(red[2], red[3]));
    __syncthreads();
    float s = 0.f;
#pragma unroll
    for (int j = 0; j < 4; j++) {
        v[j].x = expf(v[j].x - mx); v[j].y = expf(v[j].y - mx);
        v[j].z = expf(v[j].z - mx); v[j].w = expf(v[j].w - mx);
        s += v[j].x + v[j].y + v[j].z + v[j].w;
    }
    for (int m = 32; m; m >>= 1) s += __shfl_xor(s, m, 64);
    if (lane == 0) red[wave] = s;
    __syncthreads();
    s = red[0] + red[1] + red[2] + red[3];
    __syncthreads();
    float invs = 1.0f / s;
    float s2 = 0.f;
    float4* Pr = (float4*)(Pi + (size_t)bh * Nc);
#pragma unroll
    for (int j = 0; j < 4; j++) {
        float4 p;
        p.x = v[j].x * invs; p.y = v[j].y * invs;
        p.z = v[j].z * invs; p.w = v[j].w * invs;
        s2 += p.x + p.y + p.z + p.w;
        Pr[t + 256 * j] = p;
    }
    for (int m = 32; m; m >>= 1) s2 += __shfl_xor(s2, m, 64);
    if (lane == 0) red[wave] = s2;
    __syncthreads();
    if (t == 0) rowsc[bh] = 1.0f / (red[0] + red[1] + red[2] + red[3] + 1e-8f);
}

// dots[b,h,d] = sum_n Pi_n * w^2 ; w bf16, vectorized uint2 (4 bf16) per lane
__global__ __launch_bounds__(256) void dots_kernel(
    const u16* __restrict__ w, const float* __restrict__ Pi,
    const float* __restrict__ rowsc, float* __restrict__ dots) {
    int blk = blockIdx.x;
    int chunk = blk & 15, bh = blk >> 4;
    int b = bh / Hc, h = bh - b * Hc;
    int t = threadIdx.x, d4 = t & 15, rg = t >> 4;
    const u16* base = w + ((size_t)b * Nc + chunk * 256 + rg) * Dc + h * DHc + d4 * 4;
    const float* Prow = Pi + (size_t)bh * Nc + chunk * 256 + rg;
    float4 acc = {0.f, 0.f, 0.f, 0.f};
#pragma unroll 4
    for (int j = 0; j < 16; j++) {
        uint2 u = *(const uint2*)(base + (size_t)j * 16 * Dc);
        float p = Prow[j * 16];
        float a0, a1, a2, a3;
        unp2(u.x, a0, a1); unp2(u.y, a2, a3);
        acc.x += p * a0 * a0; acc.y += p * a1 * a1;
        acc.z += p * a2 * a2; acc.w += p * a3 * a3;
    }
    __shared__ float4 red[256];
    red[t] = acc;
    __syncthreads();
    if (t < 64) {
        float s = 0.f;
#pragma unroll
        for (int r = 0; r < 16; r++) {
            const float* f = (const float*)&red[r * 16 + (t >> 2)];
            s += f[t & 3];
        }
        atomicAdd(&dots[bh * DHc + t], s * rowsc[bh]);
    }
}

// attn-out: abuf = bf16( -(w*Pi) / (1+dots) ); 8 bf16 per thread
__global__ __launch_bounds__(256) void attnout_kernel(
    const u16* __restrict__ w, const float* __restrict__ Pi,
    const float* __restrict__ dots, u16* __restrict__ out) {
    int idx = blockIdx.x * 256 + threadIdx.x;       // uint4 index < Mc*Dc/8
    int cg = idx % (Dc / 8);
    int m = idx / (Dc / 8);
    int b = m >> 12, n = m & 4095;
    int c = cg * 8, h = c >> 6, d = c & 63;
    int bh = b * Hc + h;
    uint4 wv = ((const uint4*)w)[idx];
    float pi = Pi[(size_t)bh * Nc + n];
    float4 dv0 = *(const float4*)(dots + bh * DHc + d);
    float4 dv1 = *(const float4*)(dots + bh * DHc + d + 4);
    float a0, a1, a2, a3, a4, a5, a6, a7;
    unp2(wv.x, a0, a1); unp2(wv.y, a2, a3);
    unp2(wv.z, a4, a5); unp2(wv.w, a6, a7);
    union { u16 u[8]; uint4 v4; } pk;
    pk.u[0] = f2bf(-(a0 * pi) / (1.0f + dv0.x));
    pk.u[1] = f2bf(-(a1 * pi) / (1.0f + dv0.y));
    pk.u[2] = f2bf(-(a2 * pi) / (1.0f + dv0.z));
    pk.u[3] = f2bf(-(a3 * pi) / (1.0f + dv0.w));
    pk.u[4] = f2bf(-(a4 * pi) / (1.0f + dv1.x));
    pk.u[5] = f2bf(-(a5 * pi) / (1.0f + dv1.y));
    pk.u[6] = f2bf(-(a6 * pi) / (1.0f + dv1.z));
    pk.u[7] = f2bf(-(a7 * pi) / (1.0f + dv1.w));
    ((uint4*)out)[idx] = pk.v4;
}

// ---------------- host-side launch ----------------
extern "C" void kernel_launch(void* const* d_in, const int* in_sizes, int n_in,
                              void* d_out, int out_size, void* d_ws, size_t ws_size,
                              hipStream_t stream) {
    const void* x_in = d_in[0];
    const void* ln1g = d_in[1];
    const void* ln1b = d_in[2];
    const void* qkvw = d_in[3];
    const void* temp = d_in[4];
    const void* outw = d_in[5];
    const void* outb = d_in[6];
    const void* ln2g = d_in[7];
    const void* ln2b = d_in[8];
    const void* fc1w = d_in[9];
    const void* fc1b = d_in[10];
    const void* fc2w = d_in[11];
    const void* fc2b = d_in[12];

    char* p = (char*)d_ws;
    auto alloc = [&](size_t bytes) {
        void* r = (void*)p;
        p += (bytes + 255) & ~(size_t)255;
        return r;
    };
    float* xbuf = (float*)alloc((size_t)Mc * Dc * 4);        // 50.3 MB residual (fp32)
    void*  big  = alloc((size_t)Mc * HIDc * 2);              // 100.7 MB union region
    u16*   wbuf = (u16*)big;                                 //   bf16 [M,D] qkv output
    u16*   gbuf = (u16*)big;                                 //   bf16 [M,HID] gelu output
    u16*  abuf  = (u16*)alloc((size_t)Mc * Dc * 2);          // 25.2 MB bf16 activations
    const size_t QKV_T = (size_t)Dc * Dc, OUT_T = (size_t)Dc * Dc;
    const size_t FC1_T = (size_t)HIDc * Dc, FC2_T = (size_t)Dc * HIDc;
    const size_t LSTRIDE = QKV_T + OUT_T + FC1_T + FC2_T;
    u16*  wTL   = (u16*)alloc(LSTRIDE * 2);                  // 11.8 MB per-layer weightsT
    float* nrm2 = (float*)alloc((size_t)BHDc * 4);
    float* dots = (float*)alloc((size_t)BHDc * 4);           // contiguous after nrm2
    float* logit = (float*)alloc((size_t)BHc * Nc * 4);
    float* Pi    = (float*)alloc((size_t)BHc * Nc * 4);
    float* rowsc = (float*)alloc((size_t)BHc * 4);
    uint32_t* flag = (uint32_t*)alloc(256);
    float* ln1g_f = (float*)alloc((size_t)DEPTHc * Dc * 4);
    float* ln1b_f = (float*)alloc((size_t)DEPTHc * Dc * 4);
    float* ln2g_f = (float*)alloc((size_t)DEPTHc * Dc * 4);
    float* ln2b_f = (float*)alloc((size_t)DEPTHc * Dc * 4);
    float* outb_f = (float*)alloc((size_t)DEPTHc * Dc * 4);
    float* fc1b_f = (float*)alloc((size_t)DEPTHc * HIDc * 4);
    float* fc2b_f = (float*)alloc((size_t)DEPTHc * Dc * 4);
    float* temp_f = (float*)alloc((size_t)DEPTHc * Hc * 4);
    if ((size_t)(p - (char*)d_ws) > ws_size) {
        sentinel_kernel<<<(out_size + 255) / 256, 256, 0, stream>>>((u16*)d_out, out_size);
        return;
    }

    detect_kernel<<<1, 256, 0, stream>>>((const uint32_t*)x_in, flag);

    auto cvt = [&](const void* s, float* d, int n) {
        cvt_param_kernel<<<(n + 255) / 256, 256, 0, stream>>>(s, d, n, flag);
    };
    cvt(x_in, xbuf, Mc * Dc);
    cvt(ln1g, ln1g_f, DEPTHc * Dc);
    cvt(ln1b, ln1b_f, DEPTHc * Dc);
    cvt(ln2g, ln2g_f, DEPTHc * Dc);
    cvt(ln2b, ln2b_f, DEPTHc * Dc);
    cvt(outb, outb_f, DEPTHc * Dc);
    cvt(fc1b, fc1b_f, DEPTHc * HIDc);
    cvt(fc2b, fc2b_f, DEPTHc * Dc);
    cvt(temp, temp_f, DEPTHc * Hc);

    u16* qkvT = wTL;
    u16* outT = qkvT + QKV_T;
    u16* fc1T = outT + OUT_T;
    u16* fc2T = fc1T + FC1_T;

    for (int i = 0; i < DEPTHc; i++) {
        transpose_cvt_off<<<dim3(Dc / 32, Dc / 32), 256, 0, stream>>>(
            qkvw, (size_t)i * Dc * Dc, qkvT, Dc, Dc, flag);
        transpose_cvt_off<<<dim3(Dc / 32, Dc / 32), 256, 0, stream>>>(
            outw, (size_t)i * Dc * Dc, outT, Dc, Dc, flag);
        transpose_cvt_off<<<dim3(HIDc / 32, Dc / 32), 256, 0, stream>>>(
            fc1w, (size_t)i * Dc * HIDc, fc1T, Dc, HIDc, flag);
        transpose_cvt_off<<<dim3(Dc / 32, HIDc / 32), 256, 0, stream>>>(
            fc2w, (size_t)i * HIDc * Dc, fc2T, HIDc, Dc, flag);

        // h = LN1(x) -> bf16
        ln_kernel<<<Mc, 256, 0, stream>>>(xbuf, ln1g_f + i * Dc, ln1b_f + i * Dc, abuf);
        // zero nrm2+dots BEFORE qkv gemm (its epilogue accumulates nrm2)
        hipMemsetAsync(nrm2, 0, (size_t)2 * BHDc * 4, stream);
        // w = h @ qkv_w -> bf16 wbuf, fused column-sumsq into nrm2
        gemm_kernel<3><<<dim3(Dc / 256, Mc / 256), 512, 0, stream>>>(
            abuf, qkvT, nullptr, wbuf, nullptr, nullptr, nrm2, Mc, Dc, Dc);
        logits_kernel<<<BHc * 16, 256, 0, stream>>>(wbuf, nrm2, temp_f + i * Hc, logit);
        softmax_kernel<<<BHc, 256, 0, stream>>>(logit, Pi, rowsc);
        dots_kernel<<<BHc * 16, 256, 0, stream>>>(wbuf, Pi, rowsc, dots);
        attnout_kernel<<<(Mc * Dc / 8) / 256, 256, 0, stream>>>(wbuf, Pi, dots, abuf);
        // x = attnout @ out_w + out_b + x
        gemm_kernel<1><<<dim3(Dc / 256, Mc / 256), 512, 0, stream>>>(
            abuf, outT, xbuf, nullptr, outb_f + i * Dc, xbuf, nullptr, Mc, Dc, Dc);
        // h2 = LN2(x) -> bf16
        ln_kernel<<<Mc, 256, 0, stream>>>(xbuf, ln2g_f + i * Dc, ln2b_f + i * Dc, abuf);
        // g = gelu(h2 @ fc1_w + fc1_b) -> bf16 (union region; wbuf dead now)
        gemm_kernel<2><<<dim3(HIDc / 256, Mc / 256), 512, 0, stream>>>(
            abuf, fc1T, nullptr, gbuf, fc1b_f + i * HIDc, nullptr, nullptr, Mc, HIDc, Dc);
        // x = g @ fc2_w + fc2_b + x
        gemm_kernel<1><<<dim3(Dc / 256, Mc / 256), 512, 0, stream>>>(
            gbuf, fc2T, xbuf, nullptr, fc2b_f + i * Dc, xbuf, nullptr, Mc, Dc, HIDc);
    }
    hipMemcpyAsync(d_out, xbuf, (size_t)Mc * Dc * 4, hipMemcpyDeviceToDevice, stream);
}